// Round 9
// baseline (420.721 us; speedup 1.0000x reference)
//
#include <hip/hip_runtime.h>
#include <cstdint>
#include <cstddef>

// Problem constants
#define T_TOKN 16
#define NUNITS 4096
#define LPATH  32
#define NPATHS 1024
#define BNUM   8
#define VOCABN 16384

typedef __attribute__((ext_vector_type(8))) short short8;   // 8 bf16 in 4 VGPRs
typedef __attribute__((ext_vector_type(4))) float f32x4;    // MFMA accumulator

// ws float offsets.  GEMB (f32, 16.7M fl) is dead after lstm<0>; GP/POUTF/POUTB
// overlay it.  NOTE r7/r8 bug: OUTF is 16x4096x128 bf16 = 8,388,608 ushorts =
// 4,194,304 FLOATS — r7/r8 allocated 2,097,152 (halved), so OUTB overlapped
// OUTF's t>=8 half and spilled into OUTLIN -> absmax 0.09.  Fixed here.
enum : size_t {
  OFF_WHFRAG  = 0,                        // 262144 ushort: Wh frags [tf|tb|pf|pb]
  OFF_LINFRAG = 131072,                   // 65536 ushort: lin/ul B-frags
  OFF_GEMB    = 163840,                   // f32 2 x 16384 x 512 gate-interleaved
  OFF_GP      = OFF_GEMB,                 //   overlay: f32 2 x 4096 x 512 (4,194,304 fl)
  OFF_POUTF   = OFF_GEMB + 4194304,       //   overlay: bf16 32x1024x128 (2,097,152 fl)
  OFF_POUTB   = OFF_GEMB + 6291456,       //   overlay (ends at +8,388,608 < 16,777,216)
  OFF_OUTF    = OFF_GEMB + 16777216,      // token fwd h, bf16 16x4096x128 (4,194,304 fl)
  OFF_OUTB    = OFF_OUTF + 4194304,       // token bwd h (time-realigned)   (4,194,304 fl)
  OFF_OUTLIN  = OFF_OUTB + 4194304,       // f32 16x4096x128
  OFF_SCORES  = OFF_OUTLIN + 8388608,     // f32 16x4096
  OFF_TOKFEAT = OFF_SCORES + 65536,       // f32 4096x128
  OFF_INT     = OFF_TOKFEAT + 524288,     // ints: tok_len 4096 | fe 1024 | p_len 1024 | off_p 1024 | un_p 1024
  WS_FLOATS   = OFF_INT + 8192            // ~34.3M floats = 137 MB (round 1 used 139 MB OK)
};

static __device__ __forceinline__ unsigned short f2bf(float f) {
  union { float f; unsigned u; } v; v.f = f;
  unsigned r = v.u + 0x7fffu + ((v.u >> 16) & 1u);
  return (unsigned short)(r >> 16);
}
static __device__ __forceinline__ unsigned pack_bf(float a, float b) {
  return (unsigned)f2bf(a) | ((unsigned)f2bf(b) << 16);
}
static __device__ __forceinline__ float sigf(float x)      { return 1.f / (1.f + __expf(-x)); }
static __device__ __forceinline__ float tanhfast(float x)  { return 2.f / (1.f + __expf(-2.f * x)) - 1.f; }

static __device__ __forceinline__ short8 pack8(float4 a, float4 b) {
  short8 r;
  r[0] = (short)f2bf(a.x); r[1] = (short)f2bf(a.y);
  r[2] = (short)f2bf(a.z); r[3] = (short)f2bf(a.w);
  r[4] = (short)f2bf(b.x); r[5] = (short)f2bf(b.y);
  r[6] = (short)f2bf(b.z); r[7] = (short)f2bf(b.w);
  return r;
}

// ---------------------------------------------------------------------------
// prep: (a) Wh MFMA B-frags (K=128): value = Wh[g][k],
//   g = wv*64 + c4*16 + (lane&15), k = ks*32 + (lane>>4)*8 + i.
// (b) lin/ul B-frags (K=256).  (c) lengths / path metadata.
// ---------------------------------------------------------------------------
__global__ void prep_kernel(
    const float* __restrict__ tWhf, const float* __restrict__ tWhb,
    const float* __restrict__ pWhf, const float* __restrict__ pWhb,
    const float* __restrict__ linW, const float* __restrict__ ulW,
    const int* __restrict__ units, const int* __restrict__ paths,
    const int* __restrict__ upd, const int* __restrict__ ppd,
    float* __restrict__ ws, int* __restrict__ ip)
{
  int idx = blockIdx.x * 256 + threadIdx.x;
  if (idx < 262144) {
    unsigned short* wf = (unsigned short*)(ws + OFF_WHFRAG);
    int i = idx & 7, lane = (idx >> 3) & 63, c4 = (idx >> 9) & 3;
    int ks = (idx >> 11) & 3, wv = (idx >> 13) & 7, mat = idx >> 16;
    int g = wv * 64 + c4 * 16 + (lane & 15);
    int k = ks * 32 + ((lane >> 4) << 3) + i;
    const float* Wh = (mat == 0) ? tWhf : (mat == 1) ? tWhb : (mat == 2) ? pWhf : pWhb;
    wf[idx] = f2bf(Wh[g * 128 + k]);
  } else if (idx < 262144 + 65536) {
    unsigned short* lf = (unsigned short*)(ws + OFF_LINFRAG);
    int i2 = idx - 262144;
    int mat = i2 >> 15, rem = i2 & 32767;
    int i  = rem & 7;
    int lane = (rem >> 3) & 63;
    int ks = (rem >> 9) & 7;
    int ct = (rem >> 12) & 7;
    int e = ct * 16 + (lane & 15);
    int k = ks * 32 + ((lane >> 4) << 3) + i;
    const float* W = mat ? ulW : linW;
    lf[i2] = f2bf(W[e * 256 + k]);
  } else if (idx < 327680 + 4096) {
    int n = idx - 327680;
    int len = T_TOKN;
    for (int t = 0; t < T_TOKN; ++t)
      if (units[t * NUNITS + n] == 0) { len = t; break; }
    ip[n] = len;                                   // tok_len
  } else if (idx < 331776 + 1024) {
    int p = idx - 331776;
    int* fe_a  = ip + 4096;
    int* p_len = ip + 5120;
    int* off_p = ip + 6144;
    int* un_p  = ip + 7168;
    int cum = 0; int d = BNUM - 1;
    for (int dd = 0; dd < BNUM; ++dd) {
      int c2 = cum + ppd[dd];
      if (p < c2) { d = dd; break; }
      cum = c2;
    }
    int off = 0;
    for (int dd = 0; dd < d; ++dd) off += upd[dd];
    int un = upd[d];
    off_p[p] = off; un_p[p] = un;
    int f = LPATH;
    for (int t = 0; t < LPATH; ++t)
      if (paths[t * NPATHS + p] == -1) { f = t; break; }
    fe_a[p] = f;
    int pl = LPATH;
    for (int t = 0; t < LPATH; ++t) {
      int v = paths[t * NPATHS + p];
      if ((t >= f) || (v < 0) || (v > un)) { pl = t; break; }
    }
    p_len[p] = pl;
  }
}

// ---------------------------------------------------------------------------
// gx_gemm: Gx[dir][row][512] = src[row] @ W_dir^T, stored fp32 GATE-INTERLEAVED
// ([row][j][q], j = col&127, q = col>>7) so the lstm pointwise thread gets all
// 4 gates of (u,j) in one float4.
// ---------------------------------------------------------------------------
template <int NROWS>
__global__ __launch_bounds__(512) void gx_gemm(
    const float* __restrict__ src,          // [NROWS][128] f32
    const float* __restrict__ Wf, const float* __restrict__ Wb,  // [512][128]
    float* __restrict__ out)                // [2][NROWS][512] f32 interleaved
{
  __shared__ float ot[16 * 520];
  int tid = threadIdx.x, lane = tid & 63, wv = tid >> 6;
  int dir = blockIdx.y;
  int r0 = blockIdx.x * 16;
  int rb = lane & 15, quad = lane >> 4;
  const float* W = dir ? Wb : Wf;

  short8 bfr[4][4];
#pragma unroll
  for (int ks = 0; ks < 4; ++ks)
#pragma unroll
    for (int c4 = 0; c4 < 4; ++c4) {
      int g = wv * 64 + c4 * 16 + rb;
      int k0 = ks * 32 + quad * 8;
      float4 w0 = *(const float4*)&W[g * 128 + k0];
      float4 w1 = *(const float4*)&W[g * 128 + k0 + 4];
      bfr[ks][c4] = pack8(w0, w1);
    }

  f32x4 acc[4];
#pragma unroll
  for (int c4 = 0; c4 < 4; ++c4) { f32x4 z = {0.f,0.f,0.f,0.f}; acc[c4] = z; }

#pragma unroll
  for (int ks = 0; ks < 4; ++ks) {
    const float* ap = &src[(size_t)(r0 + rb) * 128 + ks * 32 + quad * 8];
    float4 a0 = *(const float4*)ap;
    float4 a1 = *(const float4*)(ap + 4);
    short8 af = pack8(a0, a1);
#pragma unroll
    for (int c4 = 0; c4 < 4; ++c4)
      acc[c4] = __builtin_amdgcn_mfma_f32_16x16x32_bf16(af, bfr[ks][c4], acc[c4], 0, 0, 0);
  }

#pragma unroll
  for (int c4 = 0; c4 < 4; ++c4) {
    int g = wv * 64 + c4 * 16 + rb;
    int j = g & 127, q = g >> 7;
#pragma unroll
    for (int r = 0; r < 4; ++r) {
      int u = quad * 4 + r;
      ot[u * 520 + j * 4 + q] = acc[c4][r];
    }
  }
  __syncthreads();

  float* o = out + (size_t)dir * NROWS * 512;
  for (int x = tid; x < 2048; x += 512) {
    int u = x >> 7, seg = x & 127;
    *(f32x4*)&o[((size_t)(r0 + u)) * 512 + seg * 4] = *(const f32x4*)&ot[u * 520 + seg * 4];
  }
}

// ---------------------------------------------------------------------------
// MFMA BiLSTM, K=128 (Wh only — x-projection precomputed into fp32 gx tables).
// 8-wave 512-thread blocks, 2 blocks/CU.  Wave owns 64 gate-cols (B resident).
// A = h-tile in LDS.  Pointwise adds gx (fp32, gate-interleaved, prefetched
// one step ahead via idx->gx chain).
// MODE 0: token (M=16, Gemb[token]).  MODE 1: path (M=4, Gp[gidx] w/ keep).
// ---------------------------------------------------------------------------
template <int MODE>
__global__ __launch_bounds__(512, 4) void lstm_kernel(
    const unsigned short* __restrict__ whfragAll,
    const float* __restrict__ biasF, const float* __restrict__ biasB,
    const float* __restrict__ gxT,       // [2][GROWS][512] f32 interleaved
    const int* __restrict__ idxsrc,
    const int* __restrict__ lens,
    const int* __restrict__ fe_a, const int* __restrict__ off_p, const int* __restrict__ un_p,
    unsigned short* __restrict__ outF, unsigned short* __restrict__ outB)
{
  constexpr int NN    = MODE ? NPATHS : NUNITS;
  constexpr int TT    = MODE ? LPATH : T_TOKN;
  constexpr int M     = MODE ? 4 : 16;
  constexpr int GROWS = MODE ? NUNITS : VOCABN;
  constexpr int ASTR  = 136;     // h-tile row stride (ushorts), 16B-aligned
  constexpr int GSTR  = 514;     // gates row stride (f32)

  __shared__ unsigned short hsh[16 * ASTR];
  __shared__ float gates[16 * GSTR];

  int tid = threadIdx.x, lane = tid & 63, wv = tid >> 6;
  int dir = blockIdx.y;
  int n0  = blockIdx.x * M;
  int rb = lane & 15, quad = lane >> 4;

  // resident Wh B-frags: wave wv owns cols [wv*64, wv*64+64)
  const unsigned short* wb = whfragAll + (size_t)((MODE ? 2 : 0) + dir) * 65536;
  short8 bfr[4][4];
#pragma unroll
  for (int ks = 0; ks < 4; ++ks)
#pragma unroll
    for (int c4 = 0; c4 < 4; ++c4)
      bfr[ks][c4] = *(const short8*)&wb[(((wv * 4 + ks) * 4 + c4) * 64 + lane) * 8];

  for (int i = tid; i < 16 * ASTR; i += 512) hsh[i] = 0;   // h0 = 0 (+pad)

  const float* gxd = gxT + (size_t)dir * GROWS * 512;
  const float* bcp = dir ? biasB : biasF;

  // pointwise thread map: token = 2 units x 2 j; path = 1 unit x 1 j
  int jX  = MODE ? (tid & 127) : ((tid & 63) * 2);
  int ugX = MODE ? (tid >> 7)  : (tid >> 6);
  float2 b2[4];
#pragma unroll
  for (int q = 0; q < 4; ++q) {
    if (MODE == 0) b2[q] = *(const float2*)&bcp[q * 128 + jX];
    else           b2[q] = make_float2(bcp[q * 128 + jX], 0.f);
  }
  float cst0[2] = {0.f, 0.f}, cst1[2] = {0.f, 0.f};
  int ulen[2];
  ulen[0] = lens[n0 + ugX * (MODE ? 1 : 2)];
  ulen[1] = (MODE == 0) ? lens[n0 + ugX * 2 + 1] : 0;

  int gfe = 0, goff = 0, gun = 0;
  if (MODE) { gfe = fe_a[n0 + ugX]; goff = off_p[n0 + ugX]; gun = un_p[n0 + ugX]; }

  // gx(0) prefetch
  f32x4 gq[2][2];                 // [unit][j-pair]: 4 gates (i,f,g,o) each
  f32x4 gxp = {0.f, 0.f, 0.f, 0.f};
  if (MODE == 0) {
#pragma unroll
    for (int i = 0; i < 2; ++i) {
      int tau = dir ? min(max(ulen[i] - 1, 0), TT - 1) : 0;
      int tok = idxsrc[tau * NN + n0 + ugX * 2 + i];
      gq[i][0] = *(const f32x4*)&gxd[(size_t)tok * 512 + jX * 4];
      gq[i][1] = *(const f32x4*)&gxd[(size_t)tok * 512 + jX * 4 + 4];
    }
  } else {
    int tau = dir ? min(max(ulen[0] - 1, 0), TT - 1) : 0;
    int v = idxsrc[tau * NN + n0 + ugX];
    if ((tau < gfe) && (v >= 0) && (v < gun))
      gxp = *(const f32x4*)&gxd[(size_t)min(v + goff, NUNITS - 1) * 512 + jX * 4];
  }
  __syncthreads();   // h-init complete

  for (int t = 0; t < TT; ++t) {
    // ---- MFMA: gates_h = h(t-1) @ Wh^T, K=128 ----
    f32x4 acc[4];
#pragma unroll
    for (int c4 = 0; c4 < 4; ++c4) { f32x4 z = {0.f,0.f,0.f,0.f}; acc[c4] = z; }
#pragma unroll
    for (int ks = 0; ks < 4; ++ks) {
      short8 af = *(const short8*)&hsh[rb * ASTR + ks * 32 + quad * 8];
#pragma unroll
      for (int c4 = 0; c4 < 4; ++c4)
        acc[c4] = __builtin_amdgcn_mfma_f32_16x16x32_bf16(af, bfr[ks][c4], acc[c4], 0, 0, 0);
    }
    // ---- idx prefetch for t+1 (overlaps MFMA/gates) ----
    int tn = (t + 1 < TT) ? t + 1 : t;
    int ntok0 = 0, ntok1 = 0, nv = 0, ntau = 0;
    if (MODE == 0) {
      int tau0 = dir ? min(max(ulen[0] - 1 - tn, 0), TT - 1) : tn;
      int tau1 = dir ? min(max(ulen[1] - 1 - tn, 0), TT - 1) : tn;
      ntok0 = idxsrc[tau0 * NN + n0 + ugX * 2];
      ntok1 = idxsrc[tau1 * NN + n0 + ugX * 2 + 1];
    } else {
      ntau = dir ? min(max(ulen[0] - 1 - tn, 0), TT - 1) : tn;
      nv = idxsrc[ntau * NN + n0 + ugX];
    }
    // ---- gates -> LDS (C-layout: col=lane&15, row=quad*4+r) ----
#pragma unroll
    for (int c4 = 0; c4 < 4; ++c4) {
      int g = wv * 64 + c4 * 16 + rb;
#pragma unroll
      for (int r = 0; r < 4; ++r)
        gates[(quad * 4 + r) * GSTR + g] = acc[c4][r];
    }
    __syncthreads();   // gates ready; all h reads done

    // ---- pointwise: sig/tanh(gates_h + gx + b) ----
    if (MODE == 0) {
#pragma unroll
      for (int i = 0; i < 2; ++i) {
        int u = ugX * 2 + i, n = n0 + u;
        float2 q0 = *(const float2*)&gates[u * GSTR + jX];
        float2 q1 = *(const float2*)&gates[u * GSTR + 128 + jX];
        float2 q2 = *(const float2*)&gates[u * GSTR + 256 + jX];
        float2 q3 = *(const float2*)&gates[u * GSTR + 384 + jX];
        float i0 = sigf(q0.x + gq[i][0][0] + b2[0].x);
        float f0 = sigf(q1.x + gq[i][0][1] + b2[1].x);
        float g0 = tanhfast(q2.x + gq[i][0][2] + b2[2].x);
        float o0 = sigf(q3.x + gq[i][0][3] + b2[3].x);
        float i1 = sigf(q0.y + gq[i][1][0] + b2[0].y);
        float f1 = sigf(q1.y + gq[i][1][1] + b2[1].y);
        float g1 = tanhfast(q2.y + gq[i][1][2] + b2[2].y);
        float o1 = sigf(q3.y + gq[i][1][3] + b2[3].y);
        float cA = f0 * cst0[i] + i0 * g0;
        float cB = f1 * cst1[i] + i1 * g1;
        cst0[i] = cA; cst1[i] = cB;
        float h0 = o0 * tanhfast(cA);
        float h1 = o1 * tanhfast(cB);
        unsigned hp = pack_bf(h0, h1);
        *(unsigned*)&hsh[u * ASTR + jX] = hp;
        if (dir == 0) {
          *(unsigned*)&outF[((size_t)t * NN + n) * 128 + jX] = hp;
        } else {
          int L = ulen[i];
          if (t < L) *(unsigned*)&outB[((size_t)(L - 1 - t) * NN + n) * 128 + jX] = hp;
          else       *(unsigned*)&outB[((size_t)t * NN + n) * 128 + jX] = 0;
        }
      }
      // gx(t+1) loads
      gq[0][0] = *(const f32x4*)&gxd[(size_t)ntok0 * 512 + jX * 4];
      gq[0][1] = *(const f32x4*)&gxd[(size_t)ntok0 * 512 + jX * 4 + 4];
      gq[1][0] = *(const f32x4*)&gxd[(size_t)ntok1 * 512 + jX * 4];
      gq[1][1] = *(const f32x4*)&gxd[(size_t)ntok1 * 512 + jX * 4 + 4];
    } else {
      int u = ugX, n = n0 + u;
      float p0 = gates[u * GSTR + jX]       + gxp[0] + b2[0].x;
      float p1 = gates[u * GSTR + 128 + jX] + gxp[1] + b2[1].x;
      float p2 = gates[u * GSTR + 256 + jX] + gxp[2] + b2[2].x;
      float p3 = gates[u * GSTR + 384 + jX] + gxp[3] + b2[3].x;
      float ig = sigf(p0), fg = sigf(p1), gg = tanhfast(p2), og = sigf(p3);
      float c = fg * cst0[0] + ig * gg;
      cst0[0] = c;
      float h = og * tanhfast(c);
      unsigned short hb = f2bf(h);
      hsh[u * ASTR + jX] = hb;
      if (dir == 0) {
        outF[((size_t)t * NN + n) * 128 + jX] = hb;
      } else {
        int L = ulen[0];
        if (t < L) outB[((size_t)(L - 1 - t) * NN + n) * 128 + jX] = hb;
        else       outB[((size_t)t * NN + n) * 128 + jX] = 0;
      }
      bool nkeep = (ntau < gfe) && (nv >= 0) && (nv < gun);
      f32x4 z = {0.f, 0.f, 0.f, 0.f};
      gxp = z;
      if (nkeep) gxp = *(const f32x4*)&gxd[(size_t)min(nv + goff, NUNITS - 1) * 512 + jX * 4];
    }
    __syncthreads();   // h(t) writes + gates reads done before next MFMA
  }
}

// ---------------------------------------------------------------------------
// MFMA GEMM: rows x 128, K=256, A = bf16 [INf|INb] from global, B resident.
// EPI 0: row-validity mask on A, f32 store.  EPI 1: + LN+tanh+attn scores.
// ---------------------------------------------------------------------------
template <int EPI>
__global__ __launch_bounds__(256) void gemm_mfma(
    const unsigned short* __restrict__ INf, const unsigned short* __restrict__ INb,
    const int* __restrict__ lens,
    const unsigned short* __restrict__ Bfrag, const float* __restrict__ bias,
    float* __restrict__ OUT, float* __restrict__ scores,
    const float* __restrict__ lng, const float* __restrict__ lnb,
    const float* __restrict__ attw, const float* __restrict__ attb,
    const int* __restrict__ units, int Nn)
{
  constexpr int OSTR = 132;
  __shared__ float outs[64 * OSTR];
  __shared__ float red1[256];
  __shared__ float red2[256];
  __shared__ float rowm[64], rowr[64];
  __shared__ float awsh[128], lgsh[128], lbsh[128];

  int tid = threadIdx.x, lane = tid & 63, wv = tid >> 6;
  int row0 = blockIdx.x * 64;
  int t = row0 / Nn, n0 = row0 % Nn;

  if (EPI == 1 && tid < 128) {
    awsh[tid] = attw[tid]; lgsh[tid] = lng[tid]; lbsh[tid] = lnb[tid];
  }

  short8 bfr[8][2];
#pragma unroll
  for (int ks = 0; ks < 8; ++ks)
#pragma unroll
    for (int c2 = 0; c2 < 2; ++c2) {
      int ct = wv * 2 + c2;
      bfr[ks][c2] = *(const short8*)&Bfrag[(((ct * 8 + ks) * 64) + lane) * 8];
    }

  int rb = lane & 15;
  int koq = (lane >> 4) << 3;
  bool val[4];
#pragma unroll
  for (int rt = 0; rt < 4; ++rt)
    val[rt] = (EPI == 1) ? true : (t < lens[n0 + rt * 16 + rb]);

  f32x4 acc[4][2];
#pragma unroll
  for (int rt = 0; rt < 4; ++rt)
#pragma unroll
    for (int c2 = 0; c2 < 2; ++c2) {
      f32x4 z = {0.f, 0.f, 0.f, 0.f};
      acc[rt][c2] = z;
    }

#pragma unroll
  for (int ks = 0; ks < 8; ++ks) {
    const unsigned short* P = (ks < 4) ? INf : INb;
    int koff = (ks & 3) * 32 + koq;
#pragma unroll
    for (int rt = 0; rt < 4; ++rt) {
      short8 a = {0, 0, 0, 0, 0, 0, 0, 0};
      if (val[rt])
        a = *(const short8*)&P[((size_t)(row0 + rt * 16 + rb)) * 128 + koff];
#pragma unroll
      for (int c2 = 0; c2 < 2; ++c2)
        acc[rt][c2] = __builtin_amdgcn_mfma_f32_16x16x32_bf16(
            a, bfr[ks][c2], acc[rt][c2], 0, 0, 0);
    }
  }

  float bc[2];
#pragma unroll
  for (int c2 = 0; c2 < 2; ++c2) bc[c2] = bias[wv * 32 + c2 * 16 + rb];
#pragma unroll
  for (int rt = 0; rt < 4; ++rt)
#pragma unroll
    for (int c2 = 0; c2 < 2; ++c2) {
      int col = wv * 32 + c2 * 16 + rb;
      int ub  = rt * 16 + ((lane >> 4) << 2);
#pragma unroll
      for (int r = 0; r < 4; ++r)
        outs[(ub + r) * OSTR + col] = acc[rt][c2][r] + bc[c2];
    }
  __syncthreads();

  int row = tid >> 2, seg = tid & 3;
  const float* rp = &outs[row * OSTR + seg * 32];
  size_t go = ((size_t)(row0 + row)) * 128 + seg * 32;

  if (EPI == 0) {
#pragma unroll
    for (int x = 0; x < 8; ++x)
      *(f32x4*)&OUT[go + x * 4] = *(const f32x4*)&rp[x * 4];
  } else {
    f32x4 v[8];
    float s = 0.f, s2 = 0.f;
#pragma unroll
    for (int x = 0; x < 8; ++x) {
      v[x] = *(const f32x4*)&rp[x * 4];
#pragma unroll
      for (int c = 0; c < 4; ++c) { s += v[x][c]; s2 += v[x][c] * v[x][c]; }
    }
    red1[tid] = s; red2[tid] = s2;
    __syncthreads();
    if (tid < 64) {
      float a = red1[tid * 4] + red1[tid * 4 + 1] + red1[tid * 4 + 2] + red1[tid * 4 + 3];
      float b = red2[tid * 4] + red2[tid * 4 + 1] + red2[tid * 4 + 2] + red2[tid * 4 + 3];
      float m = a * (1.f / 128.f);
      float var = b * (1.f / 128.f) - m * m;
      rowm[tid] = m;
      rowr[tid] = rsqrtf(var + 1e-5f);
    }
    __syncthreads();
    float m = rowm[row], rs = rowr[row];
    float sp = 0.f;
#pragma unroll
    for (int x = 0; x < 8; ++x) {
#pragma unroll
      for (int c = 0; c < 4; ++c) {
        int col = seg * 32 + x * 4 + c;
        float q = tanhfast((v[x][c] - m) * rs * lgsh[col] + lbsh[col]);
        sp += q * awsh[col];
      }
      *(f32x4*)&OUT[go + x * 4] = v[x];
    }
    red1[tid] = sp;
    __syncthreads();
    if (tid < 64) {
      float s3 = red1[tid * 4] + red1[tid * 4 + 1] + red1[tid * 4 + 2] + red1[tid * 4 + 3]
               + attb[0];
      int n = n0 + tid;
      if (units[t * NUNITS + n] == 0) s3 = -1e9f;
      scores[t * NUNITS + n] = s3;
    }
  }
}

// ---------------------------------------------------------------------------
// Softmax over T=16 + attention-weighted pooling -> tok_feat[n][e]
// ---------------------------------------------------------------------------
__global__ __launch_bounds__(128) void softmax_feat_kernel(
    const float* __restrict__ scores, const float* __restrict__ out_lin,
    float* __restrict__ tok_feat)
{
  int n = blockIdx.x;
  int e = threadIdx.x;
  float s[T_TOKN];
  float m = -1e30f;
#pragma unroll
  for (int t = 0; t < T_TOKN; ++t) { s[t] = scores[t * NUNITS + n]; m = fmaxf(m, s[t]); }
  float sum = 0.f;
#pragma unroll
  for (int t = 0; t < T_TOKN; ++t) { s[t] = expf(s[t] - m); sum += s[t]; }
  float inv = 1.f / sum;
  float a = 0.f;
#pragma unroll
  for (int t = 0; t < T_TOKN; ++t)
    a += s[t] * inv * out_lin[((size_t)t * NUNITS + n) * 128 + e];
  tok_feat[n * 128 + e] = a;
}

// ---------------------------------------------------------------------------
extern "C" void kernel_launch(void* const* d_in, const int* in_sizes, int n_in,
                              void* d_out, int out_size, void* d_ws, size_t ws_size,
                              hipStream_t stream)
{
  const int*   units = (const int*)d_in[0];
  const int*   paths = (const int*)d_in[1];
  const int*   upd   = (const int*)d_in[2];
  const int*   ppd   = (const int*)d_in[3];
  const float* emb   = (const float*)d_in[4];
  const float* tWif  = (const float*)d_in[5];
  const float* tWhf  = (const float*)d_in[6];
  const float* tbf   = (const float*)d_in[7];
  const float* tWib  = (const float*)d_in[8];
  const float* tWhb  = (const float*)d_in[9];
  const float* tbb   = (const float*)d_in[10];
  const float* linW  = (const float*)d_in[11];
  const float* linb  = (const float*)d_in[12];
  const float* lng   = (const float*)d_in[13];
  const float* lnb   = (const float*)d_in[14];
  const float* attw  = (const float*)d_in[15];
  const float* attb  = (const float*)d_in[16];
  const float* pWif  = (const float*)d_in[17];
  const float* pWhf  = (const float*)d_in[18];
  const float* pbf   = (const float*)d_in[19];
  const float* pWib  = (const float*)d_in[20];
  const float* pWhb  = (const float*)d_in[21];
  const float* pbb   = (const float*)d_in[22];
  const float* ulW   = (const float*)d_in[23];
  const float* ulb   = (const float*)d_in[24];

  float* ws = (float*)d_ws;
  int*   ip = (int*)(ws + OFF_INT);
  if (ws_size < WS_FLOATS * sizeof(float)) return;

  unsigned short* whfrag  = (unsigned short*)(ws + OFF_WHFRAG);
  unsigned short* linfrag = (unsigned short*)(ws + OFF_LINFRAG);
  unsigned short* ulfrag  = linfrag + 32768;
  float* GEMB = ws + OFF_GEMB;
  float* GP   = ws + OFF_GP;
  unsigned short* OUTF  = (unsigned short*)(ws + OFF_OUTF);
  unsigned short* OUTB  = (unsigned short*)(ws + OFF_OUTB);
  unsigned short* POUTF = (unsigned short*)(ws + OFF_POUTF);
  unsigned short* POUTB = (unsigned short*)(ws + OFF_POUTB);

  prep_kernel<<<1300, 256, 0, stream>>>(tWhf, tWhb, pWhf, pWhb, linW, ulW,
                                        units, paths, upd, ppd, ws, ip);

  gx_gemm<VOCABN><<<dim3(VOCABN / 16, 2), 512, 0, stream>>>(emb, tWif, tWib, GEMB);

  lstm_kernel<0><<<dim3(NUNITS / 16, 2), 512, 0, stream>>>(
      whfrag, tbf, tbb, GEMB, units, ip /*tok_len*/, nullptr, nullptr, nullptr,
      OUTF, OUTB);

  gemm_mfma<1><<<1024, 256, 0, stream>>>(
      OUTF, OUTB, ip /*tok_len*/, linfrag, linb,
      ws + OFF_OUTLIN, ws + OFF_SCORES, lng, lnb, attw, attb, units, NUNITS);

  softmax_feat_kernel<<<4096, 128, 0, stream>>>(ws + OFF_SCORES, ws + OFF_OUTLIN,
                                                ws + OFF_TOKFEAT);

  gx_gemm<NUNITS><<<dim3(NUNITS / 16, 2), 512, 0, stream>>>(
      ws + OFF_TOKFEAT, pWif, pWib, GP);

  lstm_kernel<1><<<dim3(NPATHS / 4, 2), 512, 0, stream>>>(
      whfrag, pbf, pbb, GP, paths, ip + 5120 /*p_len*/,
      ip + 4096 /*fe*/, ip + 6144 /*off_p*/, ip + 7168 /*un_p*/,
      POUTF, POUTB);

  gemm_mfma<0><<<512, 256, 0, stream>>>(
      POUTF, POUTB, ip + 5120 /*p_len*/, ulfrag, ulb,
      (float*)d_out, nullptr, nullptr, nullptr, nullptr, nullptr, nullptr, NPATHS);
}